// Round 2
// baseline (1304.546 us; speedup 1.0000x reference)
//
#include <hip/hip_runtime.h>
#include <stdint.h>
#include <stddef.h>

#define DEVINL __device__ __forceinline__

typedef short sv8 __attribute__((ext_vector_type(8)));
typedef unsigned short usv8 __attribute__((ext_vector_type(8)));
typedef unsigned short usv4 __attribute__((ext_vector_type(4)));
typedef float f32x4 __attribute__((ext_vector_type(4)));

constexpr int T_TOK = 4096;   // B*S
constexpr int H_DIM = 2048;
constexpr int I_DIM = 8192;
constexpr int E_NUM = 8;
constexpr int R_LORA = 16;
constexpr float SCALING = 2.0f;
constexpr int NQ = 4;                    // token quarters
constexpr int TQ = T_TOK / NQ;           // 1024 tokens per quarter
constexpr int PQ = TQ * 2;               // 2048 pairs per quarter

DEVINL float bf2f(unsigned short u) {
  union { uint32_t i; float f; } v; v.i = ((uint32_t)u) << 16; return v.f;
}
DEVINL unsigned short f2bf(float x) {
  union { float f; uint32_t i; } v; v.f = x;
  uint32_t r = v.i + 0x7FFFu + ((v.i >> 16) & 1u);   // RNE
  return (unsigned short)(r >> 16);
}

DEVINL f32x4 MFMA_BF16(sv8 a, sv8 b, f32x4 c) {
  return __builtin_amdgcn_mfma_f32_16x16x32_bf16(a, b, c, 0, 0, 0);
}

DEVINL void load16_to_lds(const void* g, void* l) {
  __builtin_amdgcn_global_load_lds(
      (const __attribute__((address_space(1))) uint32_t*)g,
      (__attribute__((address_space(3))) uint32_t*)l, 16, 0, 0);
}

// ---------------- elementwise cast f32 -> bf16 (4 elems per thread)
__global__ void cast_f32_to_bf16(const float4* __restrict__ src, usv4* __restrict__ dst) {
  long i = (long)blockIdx.x * blockDim.x + threadIdx.x;
  float4 v = src[i];
  usv4 o;
  o[0] = f2bf(v.x); o[1] = f2bf(v.y); o[2] = f2bf(v.z); o[3] = f2bf(v.w);
  dst[i] = o;
}

__global__ void zero_lcnt(int* lcnt) {
  if (threadIdx.x < E_NUM * NQ) lcnt[threadIdx.x] = 0;
}

// ---------------- router: logits, softmax(fp32), top-2 (jax tie-break),
// per-(expert,quarter) pair lists
__global__ void router_kernel(const float* __restrict__ x, const float* __restrict__ rW,
                              float* __restrict__ wbuf, int* __restrict__ idxb,
                              float* __restrict__ probs, int* __restrict__ lcnt,
                              int* __restrict__ lists) {
  const int wave = threadIdx.x >> 6, lane = threadIdx.x & 63;
  const int t = blockIdx.x * 4 + wave;
  const float* xr = x + (long)t * H_DIM;
  float acc[E_NUM];
#pragma unroll
  for (int e = 0; e < E_NUM; ++e) acc[e] = 0.f;
  for (int h = lane; h < H_DIM; h += 64) {
    float xv = xr[h];
#pragma unroll
    for (int e = 0; e < E_NUM; ++e) acc[e] += xv * rW[e * H_DIM + h];
  }
#pragma unroll
  for (int e = 0; e < E_NUM; ++e) {
#pragma unroll
    for (int off = 32; off; off >>= 1) acc[e] += __shfl_xor(acc[e], off);
  }
  if (lane == 0) {
    float mx = acc[0];
#pragma unroll
    for (int e = 1; e < E_NUM; ++e) mx = fmaxf(mx, acc[e]);
    float p[E_NUM];
    float s = 0.f;
#pragma unroll
    for (int e = 0; e < E_NUM; ++e) { p[e] = expf(acc[e] - mx); s += p[e]; }
    float inv = 1.f / s;
#pragma unroll
    for (int e = 0; e < E_NUM; ++e) p[e] *= inv;
    int e1 = 0;
    for (int e = 1; e < E_NUM; ++e) if (p[e] > p[e1]) e1 = e;       // first max
    int e2 = (e1 == 0) ? 1 : 0;
    for (int e = 0; e < E_NUM; ++e) if (e != e1 && p[e] > p[e2]) e2 = e;
    float w1 = p[e1], w2 = p[e2], wsum = w1 + w2;
    wbuf[t * 2 + 0] = w1 / wsum;
    wbuf[t * 2 + 1] = w2 / wsum;
    idxb[t * 2 + 0] = e1;
    idxb[t * 2 + 1] = e2;
#pragma unroll
    for (int e = 0; e < E_NUM; ++e) probs[(long)t * E_NUM + e] = p[e];
    const int q = t / TQ;
    int p1 = atomicAdd(&lcnt[e1 * NQ + q], 1); lists[(e1 * NQ + q) * TQ + p1] = t * 2 + 0;
    int p2 = atomicAdd(&lcnt[e2 * NQ + q], 1); lists[(e2 * NQ + q) * TQ + p2] = t * 2 + 1;
  }
}

// ---------------- aux loss: deterministic single-wave reduction
__global__ void aux_kernel(const float* __restrict__ probs, const int* __restrict__ lcnt,
                           float* __restrict__ aux_out) {
  const int lane = threadIdx.x;
  float s[E_NUM];
#pragma unroll
  for (int e = 0; e < E_NUM; ++e) s[e] = 0.f;
  for (int t = lane; t < T_TOK; t += 64) {
#pragma unroll
    for (int e = 0; e < E_NUM; ++e) s[e] += probs[(long)t * E_NUM + e];
  }
#pragma unroll
  for (int e = 0; e < E_NUM; ++e) {
#pragma unroll
    for (int off = 32; off; off >>= 1) s[e] += __shfl_xor(s[e], off);
  }
  if (lane == 0) {
    float a = 0.f;
#pragma unroll
    for (int e = 0; e < E_NUM; ++e) {
      int cnt = 0;
#pragma unroll
      for (int q = 0; q < NQ; ++q) cnt += lcnt[e * NQ + q];
      a += ((float)cnt / (float)T_TOK) * (s[e] / (float)T_TOK);
    }
    *aux_out = (float)E_NUM * a;
  }
}

// ---------------- u = x @ A.T for each selected (token,expert) pair (fp32)
__global__ void lora_a_kernel(const float* __restrict__ x, const float* __restrict__ gA,
                              const float* __restrict__ uA, const int* __restrict__ idxb,
                              float* __restrict__ ug, float* __restrict__ uu) {
  const int p = blockIdx.x;          // pair id
  const int t = p >> 1;
  const int e = idxb[p];
  const int r = threadIdx.x >> 4;    // 0..15
  const int hg = threadIdx.x & 15;   // 0..15
  const float* xr = x + (long)t * H_DIM;
  const float* ga = gA + ((long)e * R_LORA + r) * H_DIM;
  const float* ua = uA + ((long)e * R_LORA + r) * H_DIM;
  float sg = 0.f, su = 0.f;
  for (int h = hg; h < H_DIM; h += 16) {
    float xv = xr[h];
    sg += xv * ga[h];
    su += xv * ua[h];
  }
#pragma unroll
  for (int off = 8; off; off >>= 1) {
    sg += __shfl_xor(sg, off);
    su += __shfl_xor(su, off);
  }
  if (hg == 0) {
    ug[(long)p * R_LORA + r] = sg;
    uu[(long)p * R_LORA + r] = su;
  }
}

// ---------------- GEMM1: g = X@gateW.T, u = X@upW.T  (dual-B, bf16 out)
// m97 structure: 128x128 tile, BK=32, 4 waves (2x2), global_load_lds width=16
__global__ __launch_bounds__(256, 2)
void gemm1_kernel(const unsigned short* __restrict__ A,    // [T,H] bf16
                  const unsigned short* __restrict__ B0,   // [I,H] bf16
                  const unsigned short* __restrict__ B1,   // [I,H] bf16
                  unsigned short* __restrict__ C0,         // [T,I] bf16
                  unsigned short* __restrict__ C1) {
  constexpr int Kd = H_DIM;
  __shared__ unsigned short As[128 * 32];
  __shared__ unsigned short Bs0[128 * 32];
  __shared__ unsigned short Bs1[128 * 32];
  const int tid = threadIdx.x;
  const int wave = tid >> 6, lane = tid & 63;
  const int wm = wave >> 1, wn = wave & 1;
  const long m0 = (long)blockIdx.y * 128;
  const long n0 = (long)blockIdx.x * 128;
  f32x4 accG[4][4] = {}, accU[4][4] = {};
  const int srow = wave * 32 + (lane >> 2);
  const int scol = (lane & 3) * 8;
  const unsigned short* Ag  = A  + (m0 + srow) * Kd + scol;
  const unsigned short* B0g = B0 + (n0 + srow) * Kd + scol;
  const unsigned short* B1g = B1 + (n0 + srow) * Kd + scol;
  const int frA = wm * 64 + (lane & 15);
  const int frB = wn * 64 + (lane & 15);
  const int fc = (lane >> 4) * 8;

  for (int k0 = 0; k0 < Kd; k0 += 32) {
    __syncthreads();
#pragma unroll
    for (int c = 0; c < 2; ++c) {
      load16_to_lds(Ag  + (long)c * 16 * Kd + k0, &As [(wave * 32 + c * 16) * 32]);
      load16_to_lds(B0g + (long)c * 16 * Kd + k0, &Bs0[(wave * 32 + c * 16) * 32]);
      load16_to_lds(B1g + (long)c * 16 * Kd + k0, &Bs1[(wave * 32 + c * 16) * 32]);
    }
    __syncthreads();
    sv8 af[4], b0f[4], b1f[4];
#pragma unroll
    for (int m = 0; m < 4; ++m) af[m] = *(const sv8*)&As[(frA + m * 16) * 32 + fc];
#pragma unroll
    for (int n = 0; n < 4; ++n) {
      b0f[n] = *(const sv8*)&Bs0[(frB + n * 16) * 32 + fc];
      b1f[n] = *(const sv8*)&Bs1[(frB + n * 16) * 32 + fc];
    }
#pragma unroll
    for (int m = 0; m < 4; ++m)
#pragma unroll
      for (int n = 0; n < 4; ++n) {
        accG[m][n] = MFMA_BF16(af[m], b0f[n], accG[m][n]);
        accU[m][n] = MFMA_BF16(af[m], b1f[n], accU[m][n]);
      }
  }
  const int rb = (lane >> 4) * 4, cb = lane & 15;
#pragma unroll
  for (int m = 0; m < 4; ++m)
#pragma unroll
    for (int n = 0; n < 4; ++n) {
      long col = n0 + wn * 64 + n * 16 + cb;
#pragma unroll
      for (int r = 0; r < 4; ++r) {
        long row = m0 + wm * 64 + m * 16 + rb + r;
        C0[row * I_DIM + col] = f2bf(accG[m][n][r]);
        C1[row * I_DIM + col] = f2bf(accU[m][n][r]);
      }
    }
}

// ---------------- combine (per token-quarter q):
// inter[plocal] = silu(g + 2*ug@gB.T) * (u + 2*uu@uB.T)
// expert-grouped: block = (i-tile 256) x (expert, 32-pair chunk)
__global__ __launch_bounds__(256)
void combine_kernel(const unsigned short* __restrict__ g_bf,
                    const unsigned short* __restrict__ u_bf,
                    const float* __restrict__ gB, const float* __restrict__ uB,  // [E,I,R]
                    const float* __restrict__ ug, const float* __restrict__ uu,  // [T*2,R]
                    const int* __restrict__ lists, const int* __restrict__ lcnt,
                    unsigned short* __restrict__ inter, int q) {
  __shared__ float gBs[256][17];
  __shared__ float uBs[256][17];
  const int e = blockIdx.y >> 5;           // 32 chunks per (e,q)
  const int chunk = blockIdx.y & 31;
  const int npairs = lcnt[e * NQ + q];
  const int pbase = chunk * 32;
  if (pbase >= npairs) return;             // block-uniform
  const int tidx = threadIdx.x;
  const int i = blockIdx.x * 256 + tidx;
  {
    const float4* gsrc = (const float4*)(gB + ((long)e * I_DIM + i) * R_LORA);
    const float4* usrc = (const float4*)(uB + ((long)e * I_DIM + i) * R_LORA);
#pragma unroll
    for (int c = 0; c < 4; ++c) {
      float4 gv = gsrc[c], uv = usrc[c];
      gBs[tidx][c * 4 + 0] = gv.x; gBs[tidx][c * 4 + 1] = gv.y;
      gBs[tidx][c * 4 + 2] = gv.z; gBs[tidx][c * 4 + 3] = gv.w;
      uBs[tidx][c * 4 + 0] = uv.x; uBs[tidx][c * 4 + 1] = uv.y;
      uBs[tidx][c * 4 + 2] = uv.z; uBs[tidx][c * 4 + 3] = uv.w;
    }
  }
  __syncthreads();
  for (int pl = 0; pl < 32; ++pl) {
    int pi = pbase + pl;
    if (pi >= npairs) break;
    int pair = lists[(e * NQ + q) * TQ + pi];
    int t = pair >> 1;
    int plocal = pair - q * PQ;
    const float* ugp = ug + (long)pair * R_LORA;
    const float* uup = uu + (long)pair * R_LORA;
    float gd = 0.f, ud = 0.f;
#pragma unroll
    for (int r = 0; r < R_LORA; ++r) {
      gd += ugp[r] * gBs[tidx][r];
      ud += uup[r] * uBs[tidx][r];
    }
    float zg = bf2f(g_bf[(long)t * I_DIM + i]) + SCALING * gd;
    float zu = bf2f(u_bf[(long)t * I_DIM + i]) + SCALING * ud;
    float sil = zg / (1.f + expf(-zg));
    inter[(long)plocal * I_DIM + i] = f2bf(sil * zu);
  }
}

// ---------------- acc_int = w0*inter0 + w1*inter1 (bf16), token-quarter q
__global__ void acc_kernel(const unsigned short* __restrict__ inter,
                           const float* __restrict__ wbuf,
                           unsigned short* __restrict__ acc_bf, int q) {
  long gid = (long)blockIdx.x * 256 + threadIdx.x;
  int tl = (int)(gid >> 10);         // local token in quarter (I/8 = 1024 groups)
  int ig = (int)(gid & 1023);
  int t = q * TQ + tl;
  float w0 = wbuf[t * 2 + 0], w1 = wbuf[t * 2 + 1];
  usv8 a = *(const usv8*)(inter + ((long)(tl * 2 + 0)) * I_DIM + ig * 8);
  usv8 b = *(const usv8*)(inter + ((long)(tl * 2 + 1)) * I_DIM + ig * 8);
  usv8 o;
#pragma unroll
  for (int j = 0; j < 8; ++j) o[j] = f2bf(w0 * bf2f(a[j]) + w1 * bf2f(b[j]));
  *(usv8*)(acc_bf + (long)t * I_DIM + ig * 8) = o;
}

// ---------------- v = inter @ down_A.T per pair (one wave per pair), quarter q
__global__ __launch_bounds__(256)
void lora_v_kernel(const unsigned short* __restrict__ inter,
                   const unsigned short* __restrict__ dA_bf,  // [E,R,I] bf16
                   const int* __restrict__ idxb, float* __restrict__ vbuf, int q) {
  const int pl = blockIdx.x * 4 + (threadIdx.x >> 6);   // local pair in quarter
  const int lane = threadIdx.x & 63;
  const int p = q * PQ + pl;
  const int e = idxb[p];
  const unsigned short* irow = inter + (long)pl * I_DIM;
  const unsigned short* dbase = dA_bf + (long)e * R_LORA * I_DIM;
  float vr[R_LORA];
#pragma unroll
  for (int r = 0; r < R_LORA; ++r) vr[r] = 0.f;
  for (int j = 0; j < 16; ++j) {
    int ib = (lane + 64 * j) * 8;
    usv8 iv = *(const usv8*)(irow + ib);
    float fiv[8];
#pragma unroll
    for (int qq = 0; qq < 8; ++qq) fiv[qq] = bf2f(iv[qq]);
#pragma unroll
    for (int r = 0; r < R_LORA; ++r) {
      usv8 av = *(const usv8*)(dbase + (long)r * I_DIM + ib);
#pragma unroll
      for (int qq = 0; qq < 8; ++qq) vr[r] += fiv[qq] * bf2f(av[qq]);
    }
  }
#pragma unroll
  for (int r = 0; r < R_LORA; ++r) {
#pragma unroll
    for (int off = 32; off; off >>= 1) vr[r] += __shfl_xor(vr[r], off);
  }
  if (lane == 0) {
#pragma unroll
    for (int r = 0; r < R_LORA; ++r) vbuf[(long)p * R_LORA + r] = vr[r];
  }
}

// ---------------- GEMM2: out = acc_int @ downW.T + SC*sum_k w_k (v_k @ dB_e.T)
__global__ __launch_bounds__(256, 2)
void gemm2_kernel(const unsigned short* __restrict__ A,   // acc_bf [T,I]
                  const unsigned short* __restrict__ B,   // dW_bf [H,I]
                  const int* __restrict__ idxb, const float* __restrict__ wbuf,
                  const float* __restrict__ vbuf, const float* __restrict__ dB, // [E,H,R] f32
                  float* __restrict__ out) {
  constexpr int Kd = I_DIM;
  __shared__ unsigned short As[128 * 32];
  __shared__ unsigned short Bs[128 * 32];
  const int tid = threadIdx.x;
  const int wave = tid >> 6, lane = tid & 63;
  const int wm = wave >> 1, wn = wave & 1;
  const long m0 = (long)blockIdx.y * 128;
  const long n0 = (long)blockIdx.x * 128;
  f32x4 acc[4][4] = {};
  const int srow = wave * 32 + (lane >> 2);
  const int scol = (lane & 3) * 8;
  const unsigned short* Ag = A + (m0 + srow) * Kd + scol;
  const unsigned short* Bg = B + (n0 + srow) * Kd + scol;
  const int frA = wm * 64 + (lane & 15);
  const int frB = wn * 64 + (lane & 15);
  const int fc = (lane >> 4) * 8;

  for (int k0 = 0; k0 < Kd; k0 += 32) {
    __syncthreads();
#pragma unroll
    for (int c = 0; c < 2; ++c) {
      load16_to_lds(Ag + (long)c * 16 * Kd + k0, &As[(wave * 32 + c * 16) * 32]);
      load16_to_lds(Bg + (long)c * 16 * Kd + k0, &Bs[(wave * 32 + c * 16) * 32]);
    }
    __syncthreads();
    sv8 af[4], bf[4];
#pragma unroll
    for (int m = 0; m < 4; ++m) af[m] = *(const sv8*)&As[(frA + m * 16) * 32 + fc];
#pragma unroll
    for (int n = 0; n < 4; ++n) bf[n] = *(const sv8*)&Bs[(frB + n * 16) * 32 + fc];
#pragma unroll
    for (int m = 0; m < 4; ++m)
#pragma unroll
      for (int n = 0; n < 4; ++n) acc[m][n] = MFMA_BF16(af[m], bf[n], acc[m][n]);
  }

  const int rb = (lane >> 4) * 4, cb = lane & 15;
#pragma unroll
  for (int m = 0; m < 4; ++m) {
#pragma unroll
    for (int r = 0; r < 4; ++r) {
      long t = m0 + wm * 64 + m * 16 + rb + r;
      int e0 = idxb[t * 2 + 0], e1 = idxb[t * 2 + 1];
      float w0 = wbuf[t * 2 + 0], w1 = wbuf[t * 2 + 1];
      float v0[16], v1[16];
      const float4* v0p = (const float4*)(vbuf + (long)(t * 2 + 0) * R_LORA);
      const float4* v1p = (const float4*)(vbuf + (long)(t * 2 + 1) * R_LORA);
#pragma unroll
      for (int qq = 0; qq < 4; ++qq) {
        float4 a4 = v0p[qq], b4 = v1p[qq];
        v0[qq * 4 + 0] = a4.x; v0[qq * 4 + 1] = a4.y; v0[qq * 4 + 2] = a4.z; v0[qq * 4 + 3] = a4.w;
        v1[qq * 4 + 0] = b4.x; v1[qq * 4 + 1] = b4.y; v1[qq * 4 + 2] = b4.z; v1[qq * 4 + 3] = b4.w;
      }
#pragma unroll
      for (int n = 0; n < 4; ++n) {
        long col = n0 + wn * 64 + n * 16 + cb;
        const float4* b0 = (const float4*)(dB + ((long)e0 * H_DIM + col) * R_LORA);
        const float4* b1 = (const float4*)(dB + ((long)e1 * H_DIM + col) * R_LORA);
        float dd0 = 0.f, dd1 = 0.f;
#pragma unroll
        for (int qq = 0; qq < 4; ++qq) {
          float4 x0 = b0[qq], x1 = b1[qq];
          dd0 += v0[qq * 4 + 0] * x0.x + v0[qq * 4 + 1] * x0.y + v0[qq * 4 + 2] * x0.z + v0[qq * 4 + 3] * x0.w;
          dd1 += v1[qq * 4 + 0] * x1.x + v1[qq * 4 + 1] * x1.y + v1[qq * 4 + 2] * x1.z + v1[qq * 4 + 3] * x1.w;
        }
        out[t * H_DIM + col] = acc[m][n][r] + SCALING * (w0 * dd0 + w1 * dd1);
      }
    }
  }
}

// =======================================================================
extern "C" void kernel_launch(void* const* d_in, const int* in_sizes, int n_in,
                              void* d_out, int out_size, void* d_ws, size_t ws_size,
                              hipStream_t stream) {
  (void)in_sizes; (void)n_in; (void)out_size;
  const float* x        = (const float*)d_in[0];
  const float* gate_W   = (const float*)d_in[1];
  const float* up_W     = (const float*)d_in[2];
  const float* down_W   = (const float*)d_in[3];
  const float* router_W = (const float*)d_in[4];
  const float* gate_A   = (const float*)d_in[5];
  const float* gate_B   = (const float*)d_in[6];
  const float* up_A     = (const float*)d_in[7];
  const float* up_B     = (const float*)d_in[8];
  const float* down_A   = (const float*)d_in[9];
  const float* down_B   = (const float*)d_in[10];
  float* out = (float*)d_out;

  char* ws = (char*)d_ws;
  size_t off = 0;
  auto take = [&](size_t bytes) -> char* {
    char* p = ws + off;
    off += (bytes + 255) & ~(size_t)255;
    return p;
  };
  // Arena (aliased; total ~244 MB):
  unsigned short* xf_bf  = (unsigned short*)take((size_t)T_TOK * H_DIM * 2);          // 16MB
  unsigned short* gW_bf  = (unsigned short*)take((size_t)I_DIM * H_DIM * 2);          // 32MB; -> dW_bf after gemm1
  unsigned short* uW_bf  = (unsigned short*)take((size_t)I_DIM * H_DIM * 2);          // 32MB
  unsigned short* dA_bf  = (unsigned short*)take((size_t)E_NUM * R_LORA * I_DIM * 2); // 2MB
  unsigned short* g_bf   = (unsigned short*)take((size_t)T_TOK * I_DIM * 2);          // 64MB; -> acc_bf per quarter
  unsigned short* u_bf   = (unsigned short*)take((size_t)T_TOK * I_DIM * 2);          // 64MB
  unsigned short* interQ = (unsigned short*)take((size_t)PQ * I_DIM * 2);             // 32MB (quarter)
  float* wbuf  = (float*)take((size_t)T_TOK * 2 * 4);
  int*   idxb  = (int*)take((size_t)T_TOK * 2 * 4);
  float* ug    = (float*)take((size_t)T_TOK * 2 * R_LORA * 4);
  float* uu    = (float*)take((size_t)T_TOK * 2 * R_LORA * 4);
  float* vbuf  = (float*)take((size_t)T_TOK * 2 * R_LORA * 4);
  float* probs = (float*)take((size_t)T_TOK * E_NUM * 4);
  int*   lcnt  = (int*)take((size_t)E_NUM * NQ * 4);
  int*   lists = (int*)take((size_t)E_NUM * NQ * TQ * 4);

  // Aliases (stream-ordered reuse of dead buffers):
  unsigned short* dW_bf  = gW_bf;   // cast after gemm1 consumed gW_bf
  unsigned short* acc_bf = g_bf;    // acc(q) overwrites rows combine(q) already read

  if (ws_size < off) return;  // clean absmax-fail (== ref max) signals ws too small

  // 1. stats + router + aux
  zero_lcnt<<<1, 64, 0, stream>>>(lcnt);
  router_kernel<<<T_TOK / 4, 256, 0, stream>>>(x, router_W, wbuf, idxb, probs, lcnt, lists);
  aux_kernel<<<1, 64, 0, stream>>>(probs, lcnt, out + (size_t)T_TOK * H_DIM);

  // 2. casts to bf16
  cast_f32_to_bf16<<<(T_TOK * H_DIM / 4) / 256, 256, 0, stream>>>((const float4*)x, (usv4*)xf_bf);
  cast_f32_to_bf16<<<(I_DIM * H_DIM / 4) / 256, 256, 0, stream>>>((const float4*)gate_W, (usv4*)gW_bf);
  cast_f32_to_bf16<<<(I_DIM * H_DIM / 4) / 256, 256, 0, stream>>>((const float4*)up_W, (usv4*)uW_bf);
  cast_f32_to_bf16<<<(E_NUM * R_LORA * I_DIM / 4) / 256, 256, 0, stream>>>((const float4*)down_A, (usv4*)dA_bf);

  // 3. LoRA A-projections (fp32, only selected pairs)
  lora_a_kernel<<<T_TOK * 2, 256, 0, stream>>>(x, gate_A, up_A, idxb, ug, uu);

  // 4. fused gate/up base GEMM
  gemm1_kernel<<<dim3(I_DIM / 128, T_TOK / 128), 256, 0, stream>>>(xf_bf, gW_bf, uW_bf, g_bf, u_bf);

  // 5. down_W cast reuses gW_bf (dead after gemm1; same-stream ordering)
  cast_f32_to_bf16<<<(H_DIM * I_DIM / 4) / 256, 256, 0, stream>>>((const float4*)down_W, (usv4*)dW_bf);

  // 6. per token-quarter: SwiGLU+LoRA-B combine -> weighted acc -> down-LoRA v
  for (int q = 0; q < NQ; ++q) {
    combine_kernel<<<dim3(I_DIM / 256, E_NUM * 32), 256, 0, stream>>>(
        g_bf, u_bf, gate_B, up_B, ug, uu, lists, lcnt, interQ, q);
    acc_kernel<<<(TQ * (I_DIM / 8)) / 256, 256, 0, stream>>>(interQ, wbuf, acc_bf, q);
    lora_v_kernel<<<PQ / 4, 256, 0, stream>>>(interQ, dA_bf, idxb, vbuf, q);
  }

  // 7. down GEMM + fused down-LoRA epilogue
  gemm2_kernel<<<dim3(H_DIM / 128, T_TOK / 128), 256, 0, stream>>>(
      acc_bf, dW_bf, idxb, wbuf, vbuf, down_B, out);
}